// Round 2
// baseline (76.900 us; speedup 1.0000x reference)
//
#include <hip/hip_runtime.h>
#include <hip/hip_bf16.h>
#include <math.h>

#define Bn 4096
#define Ln 50
#define Cn 100
#define Tn 50000
#define Dn 128
#define H1n 256
#define H2n 128

// Kernel 1: tag_score[t] = dot(tag_table[t,:], Wr[H2 : H2+D])
// one wave (64 lanes) per row, each lane loads float2 (128 elems total)
__global__ __launch_bounds__(256) void tag_score_kernel(
    const float* __restrict__ table, const float* __restrict__ Wr,
    float* __restrict__ tag_score) {
  const int wave = (blockIdx.x * blockDim.x + threadIdx.x) >> 6;
  const int lane = threadIdx.x & 63;
  if (wave >= Tn) return;
  const float2 w = *reinterpret_cast<const float2*>(Wr + H2n + lane * 2);
  const float2 v =
      *reinterpret_cast<const float2*>(table + (size_t)wave * Dn + lane * 2);
  float acc = v.x * w.x + v.y * w.y;
#pragma unroll
  for (int m = 32; m >= 1; m >>= 1) acc += __shfl_xor(acc, m, 64);
  if (lane == 0) tag_score[wave] = acc;
}

// Kernel 2: one block (256 threads) per batch row.
// pool u/i -> x[256] -> h=relu(xW1+b1) -> mid=relu(hW2+b2) -> s_mid=mid.Wr[:128]
// -> out[b,c] = sigmoid(s_mid + tag_score[candi[b,c]] + br)
__global__ __launch_bounds__(256) void fused_kernel(
    const int* __restrict__ user_tags, const int* __restrict__ user_len,
    const int* __restrict__ item_tags, const int* __restrict__ item_len,
    const int* __restrict__ candi_tags, const float* __restrict__ table,
    const float* __restrict__ W1, const float* __restrict__ b1,
    const float* __restrict__ W2, const float* __restrict__ b2,
    const float* __restrict__ Wr, const float* __restrict__ br,
    const float* __restrict__ tag_score, float* __restrict__ out) {
  __shared__ int s_utags[Ln];
  __shared__ int s_itags[Ln];
  __shared__ int s_ctags[Cn];
  __shared__ float s_x[2 * Dn];
  __shared__ float s_h[H1n];
  __shared__ float s_red[H2n];

  const int b = blockIdx.x;
  const int tid = threadIdx.x;

  if (tid < Ln) s_utags[tid] = user_tags[b * Ln + tid];
  if (tid >= 128 && tid < 128 + Ln) s_itags[tid - 128] = item_tags[b * Ln + (tid - 128)];
  __syncthreads();

  // ---- masked-mean pooling: threads [0,128) -> user, [128,256) -> item ----
  {
    const int half = tid >> 7;          // 0 = user, 1 = item
    const int d = tid & 127;
    const int len = half ? item_len[b] : user_len[b];
    const int* tags = half ? s_itags : s_utags;
    float acc = 0.f;
#pragma unroll 4
    for (int l = 0; l < len; ++l) {
      acc += table[(size_t)tags[l] * Dn + d];
    }
    const int den = len > 0 ? len : 1;
    s_x[tid] = acc / (float)den;        // x = [u_emb | i_emb]
  }
  __syncthreads();

  // ---- h = relu(x @ W1 + b1); thread j computes output j ----
  {
    float acc = b1[tid];
#pragma unroll
    for (int k4 = 0; k4 < (2 * Dn) / 4; ++k4) {
      const float4 xv = *reinterpret_cast<const float4*>(s_x + 4 * k4);
      const int k = 4 * k4;
      acc += xv.x * W1[(k + 0) * H1n + tid];
      acc += xv.y * W1[(k + 1) * H1n + tid];
      acc += xv.z * W1[(k + 2) * H1n + tid];
      acc += xv.w * W1[(k + 3) * H1n + tid];
    }
    s_h[tid] = fmaxf(acc, 0.f);
  }
  __syncthreads();

  // ---- mid = relu(h @ W2 + b2); partials mid[j]*Wr[j]; also stage candi ----
  if (tid < H2n) {
    float acc = b2[tid];
#pragma unroll
    for (int k4 = 0; k4 < H1n / 4; ++k4) {
      const float4 hv = *reinterpret_cast<const float4*>(s_h + 4 * k4);
      const int k = 4 * k4;
      acc += hv.x * W2[(k + 0) * H2n + tid];
      acc += hv.y * W2[(k + 1) * H2n + tid];
      acc += hv.z * W2[(k + 2) * H2n + tid];
      acc += hv.w * W2[(k + 3) * H2n + tid];
    }
    const float mid = fmaxf(acc, 0.f);
    s_red[tid] = mid * Wr[tid];
  } else {
    const int c = tid - 128;
    if (c < Cn) s_ctags[c] = candi_tags[b * Cn + c];
  }
  __syncthreads();

  // ---- reduce 128 partials -> s_mid ----
#pragma unroll
  for (int s = H2n / 2; s > 0; s >>= 1) {
    if (tid < s) s_red[tid] += s_red[tid + s];
    __syncthreads();
  }
  const float s_mid = s_red[0] + br[0];

  // ---- candidate scores ----
  if (tid < Cn) {
    const float v = s_mid + tag_score[s_ctags[tid]];
    out[b * Cn + tid] = 1.f / (1.f + __expf(-v));
  }
}

extern "C" void kernel_launch(void* const* d_in, const int* in_sizes, int n_in,
                              void* d_out, int out_size, void* d_ws, size_t ws_size,
                              hipStream_t stream) {
  const int* user_tags  = (const int*)d_in[0];
  const int* user_len   = (const int*)d_in[1];
  const int* item_tags  = (const int*)d_in[2];
  const int* item_len   = (const int*)d_in[3];
  const int* candi_tags = (const int*)d_in[4];
  const float* table    = (const float*)d_in[5];
  const float* W1       = (const float*)d_in[6];
  const float* b1       = (const float*)d_in[7];
  const float* W2       = (const float*)d_in[8];
  const float* b2       = (const float*)d_in[9];
  const float* Wr       = (const float*)d_in[10];
  const float* br       = (const float*)d_in[11];
  float* out = (float*)d_out;

  float* tag_score = (float*)d_ws;  // Tn floats = 200 KB

  // Kernel 1: 4 waves/block, one wave per tag row
  const int blocks1 = (Tn + 3) / 4;
  tag_score_kernel<<<blocks1, 256, 0, stream>>>(table, Wr, tag_score);

  // Kernel 2: one block per batch row
  fused_kernel<<<Bn, 256, 0, stream>>>(user_tags, user_len, item_tags, item_len,
                                       candi_tags, table, W1, b1, W2, b2, Wr, br,
                                       tag_score, out);
}

// Round 3
// 58.308 us; speedup vs baseline: 1.3189x; 1.3189x over previous
//
#include <hip/hip_runtime.h>
#include <hip/hip_bf16.h>
#include <math.h>

#define Bn 4096
#define Ln 50
#define Cn 100
#define Tn 50000
#define Dn 128
#define H1n 256
#define H2n 128
#define Rr 8   // rows per block in mlp_score_kernel

// ---------------------------------------------------------------------------
// Kernel 1: tag_score[t] = dot(tag_table[t,:], Wr[H2 : H2+D])
// one wave (64 lanes) per row, each lane loads float2 (128 elems total)
// ---------------------------------------------------------------------------
__global__ __launch_bounds__(256) void tag_score_kernel(
    const float* __restrict__ table, const float* __restrict__ Wr,
    float* __restrict__ tag_score) {
  const int wave = (blockIdx.x * blockDim.x + threadIdx.x) >> 6;
  const int lane = threadIdx.x & 63;
  if (wave >= Tn) return;
  const float2 w = *reinterpret_cast<const float2*>(Wr + H2n + lane * 2);
  const float2 v =
      *reinterpret_cast<const float2*>(table + (size_t)wave * Dn + lane * 2);
  float acc = v.x * w.x + v.y * w.y;
#pragma unroll
  for (int m = 32; m >= 1; m >>= 1) acc += __shfl_xor(acc, m, 64);
  if (lane == 0) tag_score[wave] = acc;
}

// ---------------------------------------------------------------------------
// Kernel 2: masked-mean pooling -> x[b, 0:128]=user, x[b, 128:256]=item
// one block per batch row; 4096 blocks => deep TLP to hide gather latency
// ---------------------------------------------------------------------------
__global__ __launch_bounds__(256) void pool_kernel(
    const int* __restrict__ user_tags, const int* __restrict__ user_len,
    const int* __restrict__ item_tags, const int* __restrict__ item_len,
    const float* __restrict__ table, float* __restrict__ x_out) {
  __shared__ int s_tags[2][Ln];
  const int b = blockIdx.x;
  const int tid = threadIdx.x;

  if (tid < Ln) s_tags[0][tid] = user_tags[b * Ln + tid];
  else if (tid >= 128 && tid < 128 + Ln) s_tags[1][tid - 128] = item_tags[b * Ln + (tid - 128)];
  __syncthreads();

  const int half = tid >> 7;  // 0 = user, 1 = item
  const int d = tid & 127;
  const int len = half ? item_len[b] : user_len[b];
  const int* tags = s_tags[half];

  float acc = 0.f;
  int l = 0;
  for (; l + 4 <= len; l += 4) {  // 4 independent gather streams
    const float v0 = table[(size_t)tags[l + 0] * Dn + d];
    const float v1 = table[(size_t)tags[l + 1] * Dn + d];
    const float v2 = table[(size_t)tags[l + 2] * Dn + d];
    const float v3 = table[(size_t)tags[l + 3] * Dn + d];
    acc += (v0 + v1) + (v2 + v3);
  }
  for (; l < len; ++l) acc += table[(size_t)tags[l] * Dn + d];

  const int den = len > 0 ? len : 1;
  x_out[(size_t)b * (2 * Dn) + tid] = acc / (float)den;
}

// ---------------------------------------------------------------------------
// Kernel 3: 8 rows per block. x -> h=relu(xW1+b1) -> mid=relu(hW2+b2)
//   -> s_mid[r]=mid.Wr[:128] -> out[b,c]=sigmoid(s_mid+tag_score[candi]+br)
// Weight loads amortized 8x via register reuse.
// ---------------------------------------------------------------------------
__global__ __launch_bounds__(256) void mlp_score_kernel(
    const float* __restrict__ x_in, const float* __restrict__ W1,
    const float* __restrict__ b1, const float* __restrict__ W2,
    const float* __restrict__ b2, const float* __restrict__ Wr,
    const float* __restrict__ br, const float* __restrict__ tag_score,
    const int* __restrict__ candi_tags, float* __restrict__ out) {
  __shared__ float s_x[Rr][2 * Dn];   // 8 KB
  __shared__ float s_h[Rr][H1n];      // 8 KB
  __shared__ float s_part[4][4];      // per-wave partial reductions
  __shared__ float s_w[Rr];           // s_mid per row

  const int b0 = blockIdx.x * Rr;
  const int tid = threadIdx.x;

  // ---- stage x rows b0..b0+7 (contiguous, 2048 floats) ----
  {
    const float4* src = reinterpret_cast<const float4*>(x_in + (size_t)b0 * (2 * Dn));
    float4* dst = reinterpret_cast<float4*>(&s_x[0][0]);
#pragma unroll
    for (int i = 0; i < 2; ++i) dst[tid + 256 * i] = src[tid + 256 * i];
  }
  __syncthreads();

  // ---- layer 1: h[r][j], j = tid ----
  {
    float acc[Rr];
    const float bb = b1[tid];
#pragma unroll
    for (int r = 0; r < Rr; ++r) acc[r] = bb;
#pragma unroll 2
    for (int k4 = 0; k4 < (2 * Dn) / 4; ++k4) {
      const int k = 4 * k4;
      const float w0 = W1[(k + 0) * H1n + tid];
      const float w1 = W1[(k + 1) * H1n + tid];
      const float w2 = W1[(k + 2) * H1n + tid];
      const float w3 = W1[(k + 3) * H1n + tid];
#pragma unroll
      for (int r = 0; r < Rr; ++r) {
        const float4 xv = *reinterpret_cast<const float4*>(&s_x[r][k]);
        acc[r] = fmaf(xv.x, w0, acc[r]);
        acc[r] = fmaf(xv.y, w1, acc[r]);
        acc[r] = fmaf(xv.z, w2, acc[r]);
        acc[r] = fmaf(xv.w, w3, acc[r]);
      }
    }
#pragma unroll
    for (int r = 0; r < Rr; ++r) s_h[r][tid] = fmaxf(acc[r], 0.f);
  }
  __syncthreads();

  // ---- layer 2: mid[r][j2], j2 = tid&127, 4 rows per thread ----
  {
    const int j2 = tid & 127;
    const int rbase = (tid >> 7) * 4;
    float acc[4];
    const float bb = b2[j2];
#pragma unroll
    for (int r = 0; r < 4; ++r) acc[r] = bb;
#pragma unroll 2
    for (int k4 = 0; k4 < H1n / 4; ++k4) {
      const int k = 4 * k4;
      const float w0 = W2[(k + 0) * H2n + j2];
      const float w1 = W2[(k + 1) * H2n + j2];
      const float w2 = W2[(k + 2) * H2n + j2];
      const float w3 = W2[(k + 3) * H2n + j2];
#pragma unroll
      for (int r = 0; r < 4; ++r) {
        const float4 hv = *reinterpret_cast<const float4*>(&s_h[rbase + r][k]);
        acc[r] = fmaf(hv.x, w0, acc[r]);
        acc[r] = fmaf(hv.y, w1, acc[r]);
        acc[r] = fmaf(hv.z, w2, acc[r]);
        acc[r] = fmaf(hv.w, w3, acc[r]);
      }
    }
    // partial: mid[r]*Wr[j2]; reduce over the 64 lanes of this wave
    const float wr = Wr[j2];
    float p[4];
#pragma unroll
    for (int r = 0; r < 4; ++r) p[r] = fmaxf(acc[r], 0.f) * wr;
#pragma unroll
    for (int m = 32; m >= 1; m >>= 1) {
#pragma unroll
      for (int r = 0; r < 4; ++r) p[r] += __shfl_xor(p[r], m, 64);
    }
    const int wave = tid >> 6;
    if ((tid & 63) == 0) {
#pragma unroll
      for (int r = 0; r < 4; ++r) s_part[wave][r] = p[r];
    }
  }
  __syncthreads();

  // combine the two waves covering each row group
  if (tid < Rr) {
    const float v = (tid < 4) ? (s_part[0][tid] + s_part[1][tid])
                              : (s_part[2][tid - 4] + s_part[3][tid - 4]);
    s_w[tid] = v;
  }
  __syncthreads();

  // ---- candidate scores: 800 outputs, coalesced ----
  const float brv = br[0];
  for (int i = tid; i < Rr * Cn; i += 256) {
    const int r = i / Cn;
    const int t = candi_tags[(size_t)b0 * Cn + i];  // rows are contiguous
    const float v = s_w[r] + tag_score[t] + brv;
    out[(size_t)b0 * Cn + i] = 1.f / (1.f + __expf(-v));
  }
}

extern "C" void kernel_launch(void* const* d_in, const int* in_sizes, int n_in,
                              void* d_out, int out_size, void* d_ws, size_t ws_size,
                              hipStream_t stream) {
  const int* user_tags  = (const int*)d_in[0];
  const int* user_len   = (const int*)d_in[1];
  const int* item_tags  = (const int*)d_in[2];
  const int* item_len   = (const int*)d_in[3];
  const int* candi_tags = (const int*)d_in[4];
  const float* table    = (const float*)d_in[5];
  const float* W1       = (const float*)d_in[6];
  const float* b1       = (const float*)d_in[7];
  const float* W2       = (const float*)d_in[8];
  const float* b2       = (const float*)d_in[9];
  const float* Wr       = (const float*)d_in[10];
  const float* br       = (const float*)d_in[11];
  float* out = (float*)d_out;

  float* tag_score = (float*)d_ws;                 // Tn floats = 200 KB
  float* x_buf = (float*)((char*)d_ws + ((Tn * sizeof(float) + 255) & ~255));
  // x_buf: Bn * 256 floats = 4 MB

  // K1: tag_score (streams table sequentially, warms L3)
  tag_score_kernel<<<(Tn + 3) / 4, 256, 0, stream>>>(table, Wr, tag_score);

  // K2: pooling, one block per batch row
  pool_kernel<<<Bn, 256, 0, stream>>>(user_tags, user_len, item_tags, item_len,
                                      table, x_buf);

  // K3: MLP + scoring, 8 rows per block
  mlp_score_kernel<<<Bn / Rr, 256, 0, stream>>>(x_buf, W1, b1, W2, b2, Wr, br,
                                                tag_score, candi_tags, out);
}

// Round 4
// 38.647 us; speedup vs baseline: 1.9898x; 1.5087x over previous
//
#include <hip/hip_runtime.h>
#include <hip/hip_bf16.h>
#include <math.h>

#define Bn 4096
#define Ln 50
#define Cn 100
#define Tn 50000
#define Dn 128
#define H1n 256
#define H2n 128
#define ROWS 16                   // batch rows per mlp block

#define NPOOL Bn                  // 4096 pool blocks
#define NTAG ((Tn + 3) / 4)       // 12500 tag-score blocks (4 waves, 1 tag each)
#define NPREP 384                 // (256*256 + 128*256) / 256 transpose blocks

typedef __attribute__((ext_vector_type(8))) short short8;
typedef __attribute__((ext_vector_type(4))) float f32x4;

// ---------------------------------------------------------------------------
// Kernel 1 (merged): pool -> x bf16 | tag_score | W1/W2 cast+transpose to bf16
// ---------------------------------------------------------------------------
__global__ __launch_bounds__(256) void gather_prep_kernel(
    const int* __restrict__ user_tags, const int* __restrict__ user_len,
    const int* __restrict__ item_tags, const int* __restrict__ item_len,
    const float* __restrict__ table, const float* __restrict__ W1,
    const float* __restrict__ W2, const float* __restrict__ Wr,
    float* __restrict__ tag_score, __hip_bfloat16* __restrict__ x_out,
    __hip_bfloat16* __restrict__ W1T, __hip_bfloat16* __restrict__ W2T) {
  __shared__ int s_tags[2][Ln];
  const int blk = blockIdx.x;
  const int tid = threadIdx.x;

  if (blk < NPOOL) {
    // ---- masked-mean pooling, one block per batch row ----
    const int b = blk;
    if (tid < Ln) s_tags[0][tid] = user_tags[b * Ln + tid];
    else if (tid >= 128 && tid < 128 + Ln) s_tags[1][tid - 128] = item_tags[b * Ln + (tid - 128)];
    __syncthreads();

    const int half = tid >> 7;  // 0 = user, 1 = item
    const int d = tid & 127;
    const int len = half ? item_len[b] : user_len[b];
    const int* tags = s_tags[half];

    float acc = 0.f;
    int l = 0;
    for (; l + 4 <= len; l += 4) {
      const float v0 = table[(size_t)tags[l + 0] * Dn + d];
      const float v1 = table[(size_t)tags[l + 1] * Dn + d];
      const float v2 = table[(size_t)tags[l + 2] * Dn + d];
      const float v3 = table[(size_t)tags[l + 3] * Dn + d];
      acc += (v0 + v1) + (v2 + v3);
    }
    for (; l < len; ++l) acc += table[(size_t)tags[l] * Dn + d];

    const int den = len > 0 ? len : 1;
    x_out[(size_t)b * (2 * Dn) + tid] = __float2bfloat16(acc / (float)den);
  } else if (blk < NPOOL + NTAG) {
    // ---- tag_score[t] = dot(table[t,:], Wr[H2:H2+D]), one wave per tag ----
    const int t = (blk - NPOOL) * 4 + (tid >> 6);
    const int lane = tid & 63;
    if (t < Tn) {
      const float2 w = *reinterpret_cast<const float2*>(Wr + H2n + lane * 2);
      const float2 v = *reinterpret_cast<const float2*>(table + (size_t)t * Dn + lane * 2);
      float acc = v.x * w.x + v.y * w.y;
#pragma unroll
      for (int m = 32; m >= 1; m >>= 1) acc += __shfl_xor(acc, m, 64);
      if (lane == 0) tag_score[t] = acc;
    }
  } else {
    // ---- weight cast + transpose: W1T[j][k] = W1[k][j], W2T[j][k] = W2[k][j] ----
    int id = (blk - NPOOL - NTAG) * 256 + tid;
    if (id < H1n * H1n) {
      const int j = id >> 8, k = id & 255;
      W1T[(size_t)j * (2 * Dn) + k] = __float2bfloat16(W1[(size_t)k * H1n + j]);
    } else {
      id -= H1n * H1n;
      const int j = id >> 8, k = id & 255;  // j < 128, k < 256
      W2T[(size_t)j * H1n + k] = __float2bfloat16(W2[(size_t)k * H2n + j]);
    }
  }
}

// ---------------------------------------------------------------------------
// Kernel 2: MFMA MLP + scoring. 512 threads (8 waves), 16 batch rows/block.
//   layer1: [16x256] @ W1[256x256] -> h (LDS, bf16)
//   layer2: [16x256] @ W2[256x128] -> mid -> s_mid = mid . Wr[:128]
//   out[b,c] = sigmoid(s_mid + tag_score[candi] + br)
// mfma_f32_16x16x32_bf16: A: lane holds A[lane&15][8*(lane>>4)+i]
//                         B: lane holds B[8*(lane>>4)+i][lane&15]
//                         D: col=lane&15, row=(lane>>4)*4+reg   (m89-verified)
// ---------------------------------------------------------------------------
__global__ __launch_bounds__(512) void mlp_mfma_kernel(
    const __hip_bfloat16* __restrict__ x_in, const __hip_bfloat16* __restrict__ W1T,
    const float* __restrict__ b1, const __hip_bfloat16* __restrict__ W2T,
    const float* __restrict__ b2, const float* __restrict__ Wr,
    const float* __restrict__ br, const float* __restrict__ tag_score,
    const int* __restrict__ candi_tags, float* __restrict__ out) {
  __shared__ __hip_bfloat16 hl[ROWS][H1n + 8];  // +8 pad: breaks bank alignment
  __shared__ float s_part[8][ROWS];
  __shared__ float s_mid[ROWS];

  const int b0 = blockIdx.x * ROWS;
  const int tid = threadIdx.x;
  const int lane = tid & 63;
  const int w = tid >> 6;       // wave 0..7
  const int lr = lane & 15;     // A-row / B-col / D-col index
  const int lg = lane >> 4;     // k-group 0..3

  // ---- A-fragments: x rows b0..b0+15, K = 256 (8 k-steps of 32) ----
  short8 a[8];
  {
    const short* xb = reinterpret_cast<const short*>(x_in) +
                      (size_t)(b0 + lr) * (2 * Dn) + 8 * lg;
#pragma unroll
    for (int s = 0; s < 8; ++s) a[s] = *reinterpret_cast<const short8*>(xb + 32 * s);
  }

  // ---- layer 1: wave w covers output cols [w*32, w*32+32) ----
#pragma unroll
  for (int t = 0; t < 2; ++t) {
    const int n0 = w * 32 + t * 16;
    f32x4 acc = {0.f, 0.f, 0.f, 0.f};
    const short* wb = reinterpret_cast<const short*>(W1T) +
                      (size_t)(n0 + lr) * (2 * Dn) + 8 * lg;
#pragma unroll
    for (int s = 0; s < 8; ++s) {
      const short8 bfr = *reinterpret_cast<const short8*>(wb + 32 * s);
      acc = __builtin_amdgcn_mfma_f32_16x16x32_bf16(a[s], bfr, acc, 0, 0, 0);
    }
    const int col = n0 + lr;
    const float bias = b1[col];
#pragma unroll
    for (int r = 0; r < 4; ++r) {
      const int row = lg * 4 + r;
      hl[row][col] = __float2bfloat16(fmaxf(acc[r] + bias, 0.f));
    }
  }
  __syncthreads();

  // ---- layer 2: wave w covers output cols [w*16, w*16+16) ----
  {
    const int n0 = w * 16;
    short8 ah[8];
    const short* hb = reinterpret_cast<const short*>(&hl[0][0]) + lr * (H1n + 8) + 8 * lg;
#pragma unroll
    for (int s = 0; s < 8; ++s) ah[s] = *reinterpret_cast<const short8*>(hb + 32 * s);

    f32x4 acc = {0.f, 0.f, 0.f, 0.f};
    const short* wb = reinterpret_cast<const short*>(W2T) + (size_t)(n0 + lr) * H1n + 8 * lg;
#pragma unroll
    for (int s = 0; s < 8; ++s) {
      const short8 bfr = *reinterpret_cast<const short8*>(wb + 32 * s);
      acc = __builtin_amdgcn_mfma_f32_16x16x32_bf16(ah[s], bfr, acc, 0, 0, 0);
    }
    const int col = n0 + lr;
    const float bias = b2[col];
    const float wr = Wr[col];
    float p[4];
#pragma unroll
    for (int r = 0; r < 4; ++r) p[r] = fmaxf(acc[r] + bias, 0.f) * wr;
    // reduce across the 16 lanes (lr) sharing each row
#pragma unroll
    for (int m = 1; m <= 8; m <<= 1) {
#pragma unroll
      for (int r = 0; r < 4; ++r) p[r] += __shfl_xor(p[r], m, 64);
    }
    if (lr == 0) {
#pragma unroll
      for (int r = 0; r < 4; ++r) s_part[w][lg * 4 + r] = p[r];
    }
  }
  __syncthreads();

  if (tid < ROWS) {
    float v = 0.f;
#pragma unroll
    for (int ww = 0; ww < 8; ++ww) v += s_part[ww][tid];
    s_mid[tid] = v + br[0];
  }
  __syncthreads();

  // ---- candidate scores: 1600 outputs ----
  for (int i = tid; i < ROWS * Cn; i += 512) {
    const int r = i / Cn;
    const int tg = candi_tags[(size_t)b0 * Cn + i];
    const float v = s_mid[r] + tag_score[tg];
    out[(size_t)b0 * Cn + i] = 1.f / (1.f + __expf(-v));
  }
}

extern "C" void kernel_launch(void* const* d_in, const int* in_sizes, int n_in,
                              void* d_out, int out_size, void* d_ws, size_t ws_size,
                              hipStream_t stream) {
  const int* user_tags  = (const int*)d_in[0];
  const int* user_len   = (const int*)d_in[1];
  const int* item_tags  = (const int*)d_in[2];
  const int* item_len   = (const int*)d_in[3];
  const int* candi_tags = (const int*)d_in[4];
  const float* table    = (const float*)d_in[5];
  const float* W1       = (const float*)d_in[6];
  const float* b1       = (const float*)d_in[7];
  const float* W2       = (const float*)d_in[8];
  const float* b2       = (const float*)d_in[9];
  const float* Wr       = (const float*)d_in[10];
  const float* br       = (const float*)d_in[11];
  float* out = (float*)d_out;

  char* ws = (char*)d_ws;
  float* tag_score       = (float*)(ws);                 // 200000 B
  __hip_bfloat16* x_buf  = (__hip_bfloat16*)(ws + 204800);        // 2 MB
  __hip_bfloat16* W1T    = (__hip_bfloat16*)(ws + 204800 + 2097152);      // 128 KB
  __hip_bfloat16* W2T    = (__hip_bfloat16*)(ws + 204800 + 2097152 + 131072);  // 64 KB

  // K1: pool + tag_score + weight prep (independent phases, one grid)
  gather_prep_kernel<<<NPOOL + NTAG + NPREP, 256, 0, stream>>>(
      user_tags, user_len, item_tags, item_len, table, W1, W2, Wr,
      tag_score, x_buf, W1T, W2T);

  // K2: MFMA MLP + scoring, 16 rows per block
  mlp_mfma_kernel<<<Bn / ROWS, 512, 0, stream>>>(
      x_buf, W1T, b1, W2T, b2, Wr, br, tag_score, candi_tags, out);
}

// Round 5
// 37.781 us; speedup vs baseline: 2.0354x; 1.0229x over previous
//
#include <hip/hip_runtime.h>
#include <hip/hip_bf16.h>
#include <math.h>

#define Bn 4096
#define Ln 50
#define Cn 100
#define Tn 50000
#define Dn 128
#define H1n 256
#define H2n 128
#define ROWS 16                   // batch rows per mlp block

#define NTBLK (Tn / 4)            // 12500 table-prep blocks (4 waves, 1 row each)
#define NWPREP 384                // (256*256 + 128*256) / 256 weight-prep blocks

typedef __attribute__((ext_vector_type(8))) short short8;
typedef __attribute__((ext_vector_type(4))) float f32x4;

// ---------------------------------------------------------------------------
// Kernel 1: single streaming pass over table:
//   tableB[t] = bf16(table[t]);  tag_score[t] = dot(table[t], Wr[H2:])
// plus W1/W2 cast+transpose blocks at the tail of the grid.
// ---------------------------------------------------------------------------
__global__ __launch_bounds__(256) void prep_kernel(
    const float* __restrict__ table, const float* __restrict__ Wr,
    const float* __restrict__ W1, const float* __restrict__ W2,
    float* __restrict__ tag_score, __hip_bfloat16* __restrict__ tableB,
    __hip_bfloat16* __restrict__ W1T, __hip_bfloat16* __restrict__ W2T) {
  const int blk = blockIdx.x;
  const int tid = threadIdx.x;

  if (blk < NTBLK) {
    const int t = blk * 4 + (tid >> 6);   // one wave per table row
    const int lane = tid & 63;
    const float2 v = *reinterpret_cast<const float2*>(table + (size_t)t * Dn + lane * 2);
    const float2 w = *reinterpret_cast<const float2*>(Wr + H2n + lane * 2);
    // bf16 copy
    __hip_bfloat162 o;
    o.x = __float2bfloat16(v.x);
    o.y = __float2bfloat16(v.y);
    *reinterpret_cast<__hip_bfloat162*>(tableB + (size_t)t * Dn + lane * 2) = o;
    // dot with Wr tail
    float acc = v.x * w.x + v.y * w.y;
#pragma unroll
    for (int m = 32; m >= 1; m >>= 1) acc += __shfl_xor(acc, m, 64);
    if (lane == 0) tag_score[t] = acc;
  } else {
    // ---- weight cast + transpose: W1T[j][k] = W1[k][j], W2T[j][k] = W2[k][j] ----
    int id = (blk - NTBLK) * 256 + tid;
    if (id < H1n * H1n) {
      const int j = id >> 8, k = id & 255;
      W1T[(size_t)j * (2 * Dn) + k] = __float2bfloat16(W1[(size_t)k * H1n + j]);
    } else {
      id -= H1n * H1n;
      const int j = id >> 8, k = id & 255;  // j < 128, k < 256
      W2T[(size_t)j * H1n + k] = __float2bfloat16(W2[(size_t)k * H2n + j]);
    }
  }
}

// ---------------------------------------------------------------------------
// Kernel 2: masked-mean pooling from bf16 table. 2 batch rows per block.
// wave layout: tid>>7 = row parity, (tid>>6)&1 = user/item, lane covers 2 dims.
// Each gather = 64 lanes x 4B = 256 B coalesced (one bf16 row).
// ---------------------------------------------------------------------------
__global__ __launch_bounds__(256) void pool_kernel(
    const int* __restrict__ user_tags, const int* __restrict__ user_len,
    const int* __restrict__ item_tags, const int* __restrict__ item_len,
    const __hip_bfloat16* __restrict__ tableB, __hip_bfloat16* __restrict__ x_out) {
  __shared__ int s_tags[2][2][Ln];
  const int b2 = blockIdx.x * 2;
  const int tid = threadIdx.x;

  if (tid < 4 * Ln) {
    const int li = tid / Ln;        // 0:r0-user 1:r0-item 2:r1-user 3:r1-item
    const int pos = tid - li * Ln;
    const int row = b2 + (li >> 1);
    const int* src = (li & 1) ? item_tags : user_tags;
    s_tags[li >> 1][li & 1][pos] = src[row * Ln + pos];
  }
  __syncthreads();

  const int rp = tid >> 7;          // row parity
  const int half = (tid >> 6) & 1;  // 0 = user, 1 = item
  const int lane = tid & 63;
  const int row = b2 + rp;
  const int len = half ? item_len[row] : user_len[row];
  const int* tags = s_tags[rp][half];

  const __hip_bfloat162* base =
      reinterpret_cast<const __hip_bfloat162*>(tableB) + lane;  // + t*64

  float a0 = 0.f, a1 = 0.f;
  int l = 0;
  for (; l + 4 <= len; l += 4) {    // 4 independent gather streams
    const __hip_bfloat162 v0 = base[(size_t)tags[l + 0] * 64];
    const __hip_bfloat162 v1 = base[(size_t)tags[l + 1] * 64];
    const __hip_bfloat162 v2 = base[(size_t)tags[l + 2] * 64];
    const __hip_bfloat162 v3 = base[(size_t)tags[l + 3] * 64];
    a0 += (__bfloat162float(v0.x) + __bfloat162float(v1.x)) +
          (__bfloat162float(v2.x) + __bfloat162float(v3.x));
    a1 += (__bfloat162float(v0.y) + __bfloat162float(v1.y)) +
          (__bfloat162float(v2.y) + __bfloat162float(v3.y));
  }
  for (; l < len; ++l) {
    const __hip_bfloat162 v = base[(size_t)tags[l] * 64];
    a0 += __bfloat162float(v.x);
    a1 += __bfloat162float(v.y);
  }

  const float inv = 1.f / (float)(len > 0 ? len : 1);
  __hip_bfloat162 o;
  o.x = __float2bfloat16(a0 * inv);
  o.y = __float2bfloat16(a1 * inv);
  *reinterpret_cast<__hip_bfloat162*>(
      x_out + (size_t)row * (2 * Dn) + half * Dn + 2 * lane) = o;
}

// ---------------------------------------------------------------------------
// Kernel 3: MFMA MLP + scoring. 512 threads (8 waves), 16 batch rows/block.
// (verified absmax 0.0 in round 4 — unchanged)
// ---------------------------------------------------------------------------
__global__ __launch_bounds__(512) void mlp_mfma_kernel(
    const __hip_bfloat16* __restrict__ x_in, const __hip_bfloat16* __restrict__ W1T,
    const float* __restrict__ b1, const __hip_bfloat16* __restrict__ W2T,
    const float* __restrict__ b2, const float* __restrict__ Wr,
    const float* __restrict__ br, const float* __restrict__ tag_score,
    const int* __restrict__ candi_tags, float* __restrict__ out) {
  __shared__ __hip_bfloat16 hl[ROWS][H1n + 8];
  __shared__ float s_part[8][ROWS];
  __shared__ float s_mid[ROWS];

  const int b0 = blockIdx.x * ROWS;
  const int tid = threadIdx.x;
  const int lane = tid & 63;
  const int w = tid >> 6;
  const int lr = lane & 15;
  const int lg = lane >> 4;

  short8 a[8];
  {
    const short* xb = reinterpret_cast<const short*>(x_in) +
                      (size_t)(b0 + lr) * (2 * Dn) + 8 * lg;
#pragma unroll
    for (int s = 0; s < 8; ++s) a[s] = *reinterpret_cast<const short8*>(xb + 32 * s);
  }

#pragma unroll
  for (int t = 0; t < 2; ++t) {
    const int n0 = w * 32 + t * 16;
    f32x4 acc = {0.f, 0.f, 0.f, 0.f};
    const short* wb = reinterpret_cast<const short*>(W1T) +
                      (size_t)(n0 + lr) * (2 * Dn) + 8 * lg;
#pragma unroll
    for (int s = 0; s < 8; ++s) {
      const short8 bfr = *reinterpret_cast<const short8*>(wb + 32 * s);
      acc = __builtin_amdgcn_mfma_f32_16x16x32_bf16(a[s], bfr, acc, 0, 0, 0);
    }
    const int col = n0 + lr;
    const float bias = b1[col];
#pragma unroll
    for (int r = 0; r < 4; ++r) {
      const int row = lg * 4 + r;
      hl[row][col] = __float2bfloat16(fmaxf(acc[r] + bias, 0.f));
    }
  }
  __syncthreads();

  {
    const int n0 = w * 16;
    short8 ah[8];
    const short* hb = reinterpret_cast<const short*>(&hl[0][0]) + lr * (H1n + 8) + 8 * lg;
#pragma unroll
    for (int s = 0; s < 8; ++s) ah[s] = *reinterpret_cast<const short8*>(hb + 32 * s);

    f32x4 acc = {0.f, 0.f, 0.f, 0.f};
    const short* wb = reinterpret_cast<const short*>(W2T) + (size_t)(n0 + lr) * H1n + 8 * lg;
#pragma unroll
    for (int s = 0; s < 8; ++s) {
      const short8 bfr = *reinterpret_cast<const short8*>(wb + 32 * s);
      acc = __builtin_amdgcn_mfma_f32_16x16x32_bf16(ah[s], bfr, acc, 0, 0, 0);
    }
    const int col = n0 + lr;
    const float bias = b2[col];
    const float wr = Wr[col];
    float p[4];
#pragma unroll
    for (int r = 0; r < 4; ++r) p[r] = fmaxf(acc[r] + bias, 0.f) * wr;
#pragma unroll
    for (int m = 1; m <= 8; m <<= 1) {
#pragma unroll
      for (int r = 0; r < 4; ++r) p[r] += __shfl_xor(p[r], m, 64);
    }
    if (lr == 0) {
#pragma unroll
      for (int r = 0; r < 4; ++r) s_part[w][lg * 4 + r] = p[r];
    }
  }
  __syncthreads();

  if (tid < ROWS) {
    float v = 0.f;
#pragma unroll
    for (int ww = 0; ww < 8; ++ww) v += s_part[ww][tid];
    s_mid[tid] = v + br[0];
  }
  __syncthreads();

  for (int i = tid; i < ROWS * Cn; i += 512) {
    const int r = i / Cn;
    const int tg = candi_tags[(size_t)b0 * Cn + i];
    const float v = s_mid[r] + tag_score[tg];
    out[(size_t)b0 * Cn + i] = 1.f / (1.f + __expf(-v));
  }
}

extern "C" void kernel_launch(void* const* d_in, const int* in_sizes, int n_in,
                              void* d_out, int out_size, void* d_ws, size_t ws_size,
                              hipStream_t stream) {
  const int* user_tags  = (const int*)d_in[0];
  const int* user_len   = (const int*)d_in[1];
  const int* item_tags  = (const int*)d_in[2];
  const int* item_len   = (const int*)d_in[3];
  const int* candi_tags = (const int*)d_in[4];
  const float* table    = (const float*)d_in[5];
  const float* W1       = (const float*)d_in[6];
  const float* b1       = (const float*)d_in[7];
  const float* W2       = (const float*)d_in[8];
  const float* b2       = (const float*)d_in[9];
  const float* Wr       = (const float*)d_in[10];
  const float* br       = (const float*)d_in[11];
  float* out = (float*)d_out;

  char* ws = (char*)d_ws;
  float* tag_score       = (float*)(ws);                        // 200000 B
  __hip_bfloat16* tableB = (__hip_bfloat16*)(ws + 204800);      // 12.8 MB
  __hip_bfloat16* x_buf  = (__hip_bfloat16*)(ws + 13004800);    // 2 MB
  __hip_bfloat16* W1T    = (__hip_bfloat16*)(ws + 15101952);    // 128 KB
  __hip_bfloat16* W2T    = (__hip_bfloat16*)(ws + 15233024);    // 64 KB

  // K1: table bf16 cast + tag_score (one streaming pass) + weight prep
  prep_kernel<<<NTBLK + NWPREP, 256, 0, stream>>>(
      table, Wr, W1, W2, tag_score, tableB, W1T, W2T);

  // K2: pooling from bf16 table, 2 batch rows per block
  pool_kernel<<<Bn / 2, 256, 0, stream>>>(
      user_tags, user_len, item_tags, item_len, tableB, x_buf);

  // K3: MFMA MLP + scoring, 16 rows per block
  mlp_mfma_kernel<<<Bn / ROWS, 512, 0, stream>>>(
      x_buf, W1T, b1, W2T, b2, Wr, br, tag_score, candi_tags, out);
}